// Round 6
// baseline (164.347 us; speedup 1.0000x reference)
//
#include <hip/hip_runtime.h>
#include <math.h>

typedef _Float16 f16x8 __attribute__((ext_vector_type(8)));
typedef float f32x16 __attribute__((ext_vector_type(16)));

#define NTOK 131072
#define HDIM 128
#define ODIM 128
#define NEXP 8
// K padded to 9 kt-steps of 16: kt 0..7 = real H, kt 8 = bias row (x side = 1.0)

// ---------------------------------------------------------------------------
// Kernel 1: pack W into B-operand fragment layout (f16).
// pw flat: [e][mt(4)][kt(9)][lane(64)][j(8)] f16
// As a B-frag (v_mfma_f32_32x32x16_f16): B[k=(lane>>5)*8+j][n=o=lane&31]
// (byte-identical to the old A[m=o][k] layout — the two are mirrors).
// kt==8: k-local 0 row = b_expert[e][o], rest zero.
__global__ void pack_w(const float* __restrict__ we, const float* __restrict__ be,
                       unsigned short* __restrict__ pw){
  int f = blockIdx.x * 256 + threadIdx.x;      // 0..18431
  int l  = f & 63;
  int kt = (f >> 6) % 9;
  int emt = f / (64 * 9);
  int mt = emt & 3;
  int e  = emt >> 2;
  int o  = (mt << 5) + (l & 31);
  f16x8 vals;
#pragma unroll
  for (int j = 0; j < 8; ++j){
    int kl = ((l >> 5) << 3) + j;
    float v;
    if (kt < 8){
      int h = kt * 16 + kl;
      v = we[(e * HDIM + h) * ODIM + o];
    } else {
      v = (kl == 0) ? be[e * ODIM + o] : 0.0f;
    }
    vals[j] = (_Float16)v;
  }
  *(f16x8*)(pw + (size_t)f * 8) = vals;
}

// ---------------------------------------------------------------------------
// Kernel 2: FUSED gating + MoE FFN. 64 tokens/block, 256 threads (4 waves).
// R9 (gate-factoring restructure): g*(W_e x) = W_e*(g*x). Scale the x A-frag
// per (expert, token-lane) with v_pk_mul_f16 and let MFMA accumulate ALL
// 8 experts directly into tot0/tot1:
//   - p accumulator GONE (-16 acc regs), f32 fold GONE (replaced ~1:1 by
//     36 pk_mul per (e,tg) — VALU wash).
//   - MFMA operands SWAPPED (A = x-frag, B = w-frag; the two fragment
//     layouts are byte-identical mirrors, both built by the existing
//     verified builders). C-map becomes row=token, col(lane)=o -> epilogue
//     is 32 coalesced dword stores: LDS transpose buffer + 2 barriers GONE.
//   - frags bf16 -> f16 (enables pk_mul; BETTER precision: 10-bit mantissa).
//     Bias row (x-side 1.0) is scaled by g automatically == g*b_e. Correct.
// Register est: 32 acc + 36 transient w-frags + ~30 addr/transients ~= 100
// <= 128 -> real 4 waves/SIMD (R8 silently sat at 3: 56 arch + ~84 acc).
// Spill tripwire: WRITE_SIZE exactly 65536 KB. absmax must DROP (f16); if it
// rises, operand-swap layout is wrong -> revert.
// CRITICAL (R1-R3 lesson): accumulators are NAMED vars, every loop touching
// register arrays fully unrolled — dynamic indexing = scratch spill.
__launch_bounds__(256, 4)
__global__ void moe_fused(const float* __restrict__ x, const float* __restrict__ wg,
                          const unsigned short* __restrict__ pw, float* __restrict__ out){
  __shared__ char lds[33792 + 4096 + 2048];
  float* xs            = (float*)lds;                 // [tok(64)][132] f32
  unsigned short* frag = (unsigned short*)lds;        // overlay: [tg2][kt9][l64][j8] f16
  float* wgt           = (float*)(lds + 33792);       // [e8][h128] f32 (transposed)
  float* glds          = (float*)(lds + 33792 + 4096);// [e8][tok64] f32

  int t = threadIdx.x;
  size_t tokbase = (size_t)blockIdx.x * 64;

  // --- stage w_gate TRANSPOSED (wgt[e][h] = wg[h][e]) + x tile
  {
    float4 v = ((const float4*)wg)[t];   // wg[h = t>>1][e = (t&1)*4 + j]
    int h = t >> 1, e0 = (t & 1) * 4;
    wgt[(e0 + 0) * 128 + h] = v.x;       // 2-way bank alias only: free
    wgt[(e0 + 1) * 128 + h] = v.y;
    wgt[(e0 + 2) * 128 + h] = v.z;
    wgt[(e0 + 3) * 128 + h] = v.w;
  }
  {
    const float4* xsrc = (const float4*)(x + tokbase * HDIM);
#pragma unroll
    for (int i = 0; i < 8; ++i){
      int idx = i * 256 + t;
      int tok = idx >> 5, c = idx & 31;
      *(float4*)&xs[tok * 132 + c * 4] = xsrc[idx];
    }
  }
  __syncthreads();

  // --- conversion-source reads (regs for the f16 frag build; dead before e-loop)
  float4 cv[8];
#pragma unroll
  for (int i = 0; i < 8; ++i)
    cv[i] = *(float4*)&xs[(t >> 2) * 132 + (t & 3) * 32 + i * 4];

  // --- gating: ALL threads. thread t -> token t&63, expert pair (2w, 2w+1).
  // wgt reads are wave-uniform (w = t>>6 constant per wave) -> LDS broadcast.
  // Summation order per expert identical to prior rounds (no top-k flip risk).
  {
    int tok = t & 63;
    const float* w0 = wgt + (t >> 6) * 2 * 128;
    const float* w1 = w0 + 128;
    float lg0 = 0.0f, lg1 = 0.0f;
#pragma unroll 8
    for (int c = 0; c < 32; ++c){
      float4 v = *(float4*)&xs[tok * 132 + c * 4];
      lg0 += v.x * w0[c * 4] + v.y * w0[c * 4 + 1] + v.z * w0[c * 4 + 2] + v.w * w0[c * 4 + 3];
      lg1 += v.x * w1[c * 4] + v.y * w1[c * 4 + 1] + v.z * w1[c * 4 + 2] + v.w * w1[c * 4 + 3];
    }
    int e0 = (t >> 6) * 2;
    glds[e0 * 64 + tok] = lg0;           // lanes have distinct tok: conflict-free
    glds[(e0 + 1) * 64 + tok] = lg1;
  }
  __syncthreads();   // xs reads (cv + gating) done; all logits in glds

  // --- top-2 + softmax (wave 0; column t is thread-exclusive: in-place safe)
  if (t < 64){
    float lg[8];
#pragma unroll
    for (int e = 0; e < 8; ++e) lg[e] = glds[e * 64 + t];
    int i1 = 0; float v1 = lg[0];
#pragma unroll
    for (int e = 1; e < 8; ++e) if (lg[e] > v1){ v1 = lg[e]; i1 = e; }
    int i2 = -1; float v2 = -3.4e38f;
#pragma unroll
    for (int e = 0; e < 8; ++e) if (e != i1 && lg[e] > v2){ v2 = lg[e]; i2 = e; }
    float ex = __expf(v2 - v1);
    float inv = 1.0f / (1.0f + ex);
#pragma unroll
    for (int e = 0; e < 8; ++e)
      glds[e * 64 + t] = (e == i1) ? inv : ((e == i2) ? ex * inv : 0.0f);
  }

  // --- convert f32 regs -> f16 A-frags (overlaid on xs; xs dead now)
  // A-frag: A[m=token][k=(lane>>5)*8+j]; lane slot = (token&31) + 32*(k>=8)
  // (same slotting as the old B-frag build — layouts are mirrors).
  {
    int tokL = t >> 2, q = t & 3, tg = tokL >> 5;
#pragma unroll
    for (int jb = 0; jb < 4; ++jb){
      int h0 = q * 32 + jb * 8;
      int kt = h0 >> 4;
      int lslot = (tokL & 31) + 32 * ((h0 >> 3) & 1);
      float4 a = cv[2 * jb], b = cv[2 * jb + 1];
      f16x8 fv;
      fv[0] = (_Float16)a.x; fv[1] = (_Float16)a.y;
      fv[2] = (_Float16)a.z; fv[3] = (_Float16)a.w;
      fv[4] = (_Float16)b.x; fv[5] = (_Float16)b.y;
      fv[6] = (_Float16)b.z; fv[7] = (_Float16)b.w;
      *(f16x8*)&frag[(((tg * 9) + kt) * 64 + lslot) * 8] = fv;
    }
    // bias kt=8 slots: 128 slots (2 tg x 64 l); f16 1.0 = 0x3C00 at j==0, k<8 half
    if (t < 128){
      int btg = t >> 6, bl = t & 63;
      unsigned long long* dst =
        (unsigned long long*)&frag[(((btg * 9) + 8) * 64 + bl) * 8];
      dst[0] = (bl < 32) ? 0x3C00ull : 0ull;
      dst[1] = 0ull;
    }
  }
  __syncthreads();   // frags + gates ready

  // --- Phase B: MFMA. C[token][o] = sum_h (g*x)[token][h] * W[h][o]
  // A = gate-scaled x-frag (from LDS, scaled in-reg), B = w-frag (streamed,
  // 9 held per expert). MFMA accumulates across ALL experts into tot0/tot1.
  int w = t >> 6, l = t & 63, l32 = l & 31, lh = l >> 5;

  f32x16 zero16;
#pragma unroll
  for (int i = 0; i < 16; ++i) zero16[i] = 0.0f;
  f32x16 tot0 = zero16, tot1 = zero16;

  const f16x8* pwp = (const f16x8*)pw;
#pragma unroll 1
  for (int e = 0; e < 8; ++e){
    float g0 = glds[e * 64 + l32];        // token = l32 (tg0): per-lane gate
    float g1 = glds[e * 64 + 32 + l32];   // token = 32+l32 (tg1)
    _Float16 g0h = (_Float16)g0, g1h = (_Float16)g1;
    f16x8 g0v = {g0h, g0h, g0h, g0h, g0h, g0h, g0h, g0h};
    f16x8 g1v = {g1h, g1h, g1h, g1h, g1h, g1h, g1h, g1h};
    const f16x8* ap = pwp + ((size_t)(e * 4 + w) * 9) * 64 + l;
    // hold the expert's 9 w-frags (36 VGPR): pw streamed ONCE per (e,wave)
    f16x8 b0 = ap[0 * 64], b1 = ap[1 * 64], b2 = ap[2 * 64],
          b3 = ap[3 * 64], b4 = ap[4 * 64], b5 = ap[5 * 64],
          b6 = ap[6 * 64], b7 = ap[7 * 64], b8 = ap[8 * 64];
    f16x8 xa;
    xa = *(const f16x8*)&frag[((0 * 9 + 0) * 64 + l) * 8];
    tot0 = __builtin_amdgcn_mfma_f32_32x32x16_f16(xa * g0v, b0, tot0, 0, 0, 0);
    xa = *(const f16x8*)&frag[((1 * 9 + 0) * 64 + l) * 8];
    tot1 = __builtin_amdgcn_mfma_f32_32x32x16_f16(xa * g1v, b0, tot1, 0, 0, 0);
    xa = *(const f16x8*)&frag[((0 * 9 + 1) * 64 + l) * 8];
    tot0 = __builtin_amdgcn_mfma_f32_32x32x16_f16(xa * g0v, b1, tot0, 0, 0, 0);
    xa = *(const f16x8*)&frag[((1 * 9 + 1) * 64 + l) * 8];
    tot1 = __builtin_amdgcn_mfma_f32_32x32x16_f16(xa * g1v, b1, tot1, 0, 0, 0);
    xa = *(const f16x8*)&frag[((0 * 9 + 2) * 64 + l) * 8];
    tot0 = __builtin_amdgcn_mfma_f32_32x32x16_f16(xa * g0v, b2, tot0, 0, 0, 0);
    xa = *(const f16x8*)&frag[((1 * 9 + 2) * 64 + l) * 8];
    tot1 = __builtin_amdgcn_mfma_f32_32x32x16_f16(xa * g1v, b2, tot1, 0, 0, 0);
    xa = *(const f16x8*)&frag[((0 * 9 + 3) * 64 + l) * 8];
    tot0 = __builtin_amdgcn_mfma_f32_32x32x16_f16(xa * g0v, b3, tot0, 0, 0, 0);
    xa = *(const f16x8*)&frag[((1 * 9 + 3) * 64 + l) * 8];
    tot1 = __builtin_amdgcn_mfma_f32_32x32x16_f16(xa * g1v, b3, tot1, 0, 0, 0);
    xa = *(const f16x8*)&frag[((0 * 9 + 4) * 64 + l) * 8];
    tot0 = __builtin_amdgcn_mfma_f32_32x32x16_f16(xa * g0v, b4, tot0, 0, 0, 0);
    xa = *(const f16x8*)&frag[((1 * 9 + 4) * 64 + l) * 8];
    tot1 = __builtin_amdgcn_mfma_f32_32x32x16_f16(xa * g1v, b4, tot1, 0, 0, 0);
    xa = *(const f16x8*)&frag[((0 * 9 + 5) * 64 + l) * 8];
    tot0 = __builtin_amdgcn_mfma_f32_32x32x16_f16(xa * g0v, b5, tot0, 0, 0, 0);
    xa = *(const f16x8*)&frag[((1 * 9 + 5) * 64 + l) * 8];
    tot1 = __builtin_amdgcn_mfma_f32_32x32x16_f16(xa * g1v, b5, tot1, 0, 0, 0);
    xa = *(const f16x8*)&frag[((0 * 9 + 6) * 64 + l) * 8];
    tot0 = __builtin_amdgcn_mfma_f32_32x32x16_f16(xa * g0v, b6, tot0, 0, 0, 0);
    xa = *(const f16x8*)&frag[((1 * 9 + 6) * 64 + l) * 8];
    tot1 = __builtin_amdgcn_mfma_f32_32x32x16_f16(xa * g1v, b6, tot1, 0, 0, 0);
    xa = *(const f16x8*)&frag[((0 * 9 + 7) * 64 + l) * 8];
    tot0 = __builtin_amdgcn_mfma_f32_32x32x16_f16(xa * g0v, b7, tot0, 0, 0, 0);
    xa = *(const f16x8*)&frag[((1 * 9 + 7) * 64 + l) * 8];
    tot1 = __builtin_amdgcn_mfma_f32_32x32x16_f16(xa * g1v, b7, tot1, 0, 0, 0);
    xa = *(const f16x8*)&frag[((0 * 9 + 8) * 64 + l) * 8];
    tot0 = __builtin_amdgcn_mfma_f32_32x32x16_f16(xa * g0v, b8, tot0, 0, 0, 0);
    xa = *(const f16x8*)&frag[((1 * 9 + 8) * 64 + l) * 8];
    tot1 = __builtin_amdgcn_mfma_f32_32x32x16_f16(xa * g1v, b8, tot1, 0, 0, 0);
  }

  // --- epilogue: direct coalesced stores (C-map: row=token, col(lane)=o).
  // token_r = tg*32 + (r&3) + 8*(r>>2) + 4*lh; o = w*32 + l32.
  // Per store: lanes 0-31 -> one 128B segment, lanes 32-63 -> another. No LDS.
#pragma unroll
  for (int r = 0; r < 16; ++r){
    int tr = (r & 3) + 8 * (r >> 2) + 4 * lh;
    out[(tokbase + tr) * ODIM + w * 32 + l32]      = tot0[r];
    out[(tokbase + 32 + tr) * ODIM + w * 32 + l32] = tot1[r];
  }
}

// ---------------------------------------------------------------------------
extern "C" void kernel_launch(void* const* d_in, const int* in_sizes, int n_in,
                              void* d_out, int out_size, void* d_ws, size_t ws_size,
                              hipStream_t stream){
  const float* x  = (const float*)d_in[0];
  const float* wg = (const float*)d_in[1];
  // d_in[2] = w_noise (inactive in eval mode)
  const float* we = (const float*)d_in[3];
  const float* be = (const float*)d_in[4];
  // d_in[5] = top_k (== 2, baked in)
  float* out = (float*)d_out;

  unsigned short* pw = (unsigned short*)d_ws;          // 294,912 B

  pack_w   <<<72,   256, 0, stream>>>(we, be, pw);
  moe_fused<<<2048, 256, 0, stream>>>(x, wg, pw, out);
}

// Round 7
// 154.839 us; speedup vs baseline: 1.0614x; 1.0614x over previous
//
#include <hip/hip_runtime.h>
#include <math.h>

typedef __bf16 bf16x8 __attribute__((ext_vector_type(8)));
typedef float f32x16 __attribute__((ext_vector_type(16)));

#define NTOK 131072
#define HDIM 128
#define ODIM 128
#define NEXP 8
// K padded to 9 kt-steps of 16: kt 0..7 = real H, kt 8 = bias row (x side = 1.0)

__device__ __forceinline__ unsigned short f2bf(float f){
  union { float f; unsigned u; } v; v.f = f;
  unsigned r = v.u + 0x7FFFu + ((v.u >> 16) & 1u);
  return (unsigned short)(r >> 16);
}

// ---------------------------------------------------------------------------
// Kernel 1: pack W into A-operand fragment layout (transposed GEMM: A[m=o][k=h])
// pw flat: [e][mt(4)][kt(9)][lane(64)][j(8)] bf16
// A-frag (v_mfma_f32_32x32x16_bf16): A[m=lane&31][k=(lane>>5)*8+j]
// kt==8: k-local 0 row = b_expert[e][o], rest zero.
__global__ void pack_w(const float* __restrict__ we, const float* __restrict__ be,
                       unsigned short* __restrict__ pw){
  int f = blockIdx.x * 256 + threadIdx.x;      // 0..18431
  int l  = f & 63;
  int kt = (f >> 6) % 9;
  int emt = f / (64 * 9);
  int mt = emt & 3;
  int e  = emt >> 2;
  int o  = (mt << 5) + (l & 31);
  unsigned short vals[8];
#pragma unroll
  for (int j = 0; j < 8; ++j){
    int kl = ((l >> 5) << 3) + j;
    float v;
    if (kt < 8){
      int h = kt * 16 + kl;
      v = we[(e * HDIM + h) * ODIM + o];
    } else {
      v = (kl == 0) ? be[e * ODIM + o] : 0.0f;
    }
    vals[j] = f2bf(v);
  }
  *(bf16x8*)(pw + (size_t)f * 8) = *(bf16x8*)vals;
}

// ---------------------------------------------------------------------------
// Kernel 2: FUSED gating + MoE FFN. 64 tokens/block, 256 threads (4 waves).
// LDS 39 KiB: xs f32 (33 KiB; later overlaid by bf16 frags (18 KiB), then by
// f32 transpose buf (32 KiB)) + wgt 4 KiB + glds 2 KiB.
// R10 (pipe round): corrected model — bank-conflict counter is noise
// (~544 cyc/block); the dominant PIPE is LDS THROUGHPUT: e-loop frag
// re-reads (144 ds_read_b128/wave) = ~1.2 GB device LDS ~= 23 us, vs L2-pw
// 17.5 us, HBM ~16, MFMA 3.8. Occupancy ladder (2w->71.5, 3w->63.4,
// 4w->62.9) is exhausted. Untested cell: zero-LDS e-loop AT 3 waves —
// R0's e-loop (both tg x-frags held in 72 regs, transient a, dual p0/p1,
// bf16 — numerics identical to R8) under (256,3). Tight-alloc est ~156
// <= 170 cap. e-loop LDS -> 0. R9's pk_mul gate-factoring REVERTED (it
// starved the MFMA pipe: every MFMA waited on 4 pk_mul).
// Spill tripwire: WRITE_SIZE exactly 65536 KB (xb spill would balloon it);
// fallback = hold tg0 frags only (36 regs), tg1 from LDS.
// CRITICAL (R1-R3 lesson): accumulators are NAMED vars / fully-unrolled
// constant-index arrays only — dynamic indexing = scratch spill.
__launch_bounds__(256, 3)
__global__ void moe_fused(const float* __restrict__ x, const float* __restrict__ wg,
                          const unsigned short* __restrict__ pw, float* __restrict__ out){
  __shared__ char lds[33792 + 4096 + 2048];
  float* xs            = (float*)lds;                 // [tok(64)][132] f32
  unsigned short* frag = (unsigned short*)lds;        // overlay: [tg2][kt9][l64][j8]
  float* tb            = (float*)lds;                 // overlay: [trow64][128] f32
  float* wgt           = (float*)(lds + 33792);       // [e8][h128] f32 (transposed)
  float* glds          = (float*)(lds + 33792 + 4096);// [e8][tok64] f32

  int t = threadIdx.x;
  size_t tokbase = (size_t)blockIdx.x * 64;

  // --- stage w_gate TRANSPOSED (wgt[e][h] = wg[h][e]) + x tile
  {
    float4 v = ((const float4*)wg)[t];   // wg[h = t>>1][e = (t&1)*4 + j]
    int h = t >> 1, e0 = (t & 1) * 4;
    wgt[(e0 + 0) * 128 + h] = v.x;       // 2-way bank alias only: free
    wgt[(e0 + 1) * 128 + h] = v.y;
    wgt[(e0 + 2) * 128 + h] = v.z;
    wgt[(e0 + 3) * 128 + h] = v.w;
  }
  {
    const float4* xsrc = (const float4*)(x + tokbase * HDIM);
#pragma unroll
    for (int i = 0; i < 8; ++i){
      int idx = i * 256 + t;
      int tok = idx >> 5, c = idx & 31;
      *(float4*)&xs[tok * 132 + c * 4] = xsrc[idx];
    }
  }
  __syncthreads();

  // --- conversion-source reads (regs for the bf16 frag build; dead before e-loop)
  float4 cv[8];
#pragma unroll
  for (int i = 0; i < 8; ++i)
    cv[i] = *(float4*)&xs[(t >> 2) * 132 + (t & 3) * 32 + i * 4];

  // --- gating: ALL threads. thread t -> token t&63, expert pair (2w, 2w+1).
  // wgt reads are wave-uniform (w = t>>6 constant per wave) -> LDS broadcast.
  // Summation order per expert identical to prior rounds (no top-k flip risk).
  {
    int tok = t & 63;
    const float* w0 = wgt + (t >> 6) * 2 * 128;
    const float* w1 = w0 + 128;
    float lg0 = 0.0f, lg1 = 0.0f;
#pragma unroll 8
    for (int c = 0; c < 32; ++c){
      float4 v = *(float4*)&xs[tok * 132 + c * 4];
      lg0 += v.x * w0[c * 4] + v.y * w0[c * 4 + 1] + v.z * w0[c * 4 + 2] + v.w * w0[c * 4 + 3];
      lg1 += v.x * w1[c * 4] + v.y * w1[c * 4 + 1] + v.z * w1[c * 4 + 2] + v.w * w1[c * 4 + 3];
    }
    int e0 = (t >> 6) * 2;
    glds[e0 * 64 + tok] = lg0;           // lanes have distinct tok: conflict-free
    glds[(e0 + 1) * 64 + tok] = lg1;
  }
  __syncthreads();   // xs reads (cv + gating) done; all logits in glds

  // --- top-2 + softmax (wave 0; column t is thread-exclusive: in-place safe)
  if (t < 64){
    float lg[8];
#pragma unroll
    for (int e = 0; e < 8; ++e) lg[e] = glds[e * 64 + t];
    int i1 = 0; float v1 = lg[0];
#pragma unroll
    for (int e = 1; e < 8; ++e) if (lg[e] > v1){ v1 = lg[e]; i1 = e; }
    int i2 = -1; float v2 = -3.4e38f;
#pragma unroll
    for (int e = 0; e < 8; ++e) if (e != i1 && lg[e] > v2){ v2 = lg[e]; i2 = e; }
    float ex = __expf(v2 - v1);
    float inv = 1.0f / (1.0f + ex);
#pragma unroll
    for (int e = 0; e < 8; ++e)
      glds[e * 64 + t] = (e == i1) ? inv : ((e == i2) ? ex * inv : 0.0f);
  }

  // --- convert f32 regs -> bf16 B-frags (overlaid on xs; xs dead now)
  // B-frag: B[k=(lane>>5)*8+j][n=lane&31] = x[token=tg*32+(lane&31)][h=kt*16+k]
  {
    int tokL = t >> 2, q = t & 3, tg = tokL >> 5;
#pragma unroll
    for (int jb = 0; jb < 4; ++jb){
      int h0 = q * 32 + jb * 8;
      int kt = h0 >> 4;
      int lslot = (tokL & 31) + 32 * ((h0 >> 3) & 1);
      float4 a = cv[2 * jb], b = cv[2 * jb + 1];
      unsigned long long lo = (unsigned long long)f2bf(a.x)
                            | ((unsigned long long)f2bf(a.y) << 16)
                            | ((unsigned long long)f2bf(a.z) << 32)
                            | ((unsigned long long)f2bf(a.w) << 48);
      unsigned long long hi = (unsigned long long)f2bf(b.x)
                            | ((unsigned long long)f2bf(b.y) << 16)
                            | ((unsigned long long)f2bf(b.z) << 32)
                            | ((unsigned long long)f2bf(b.w) << 48);
      unsigned long long* dst =
        (unsigned long long*)&frag[(((tg * 9) + kt) * 64 + lslot) * 8];
      dst[0] = lo; dst[1] = hi;
    }
    // bias kt=8 slots: 128 slots (2 tg x 64 l)
    if (t < 128){
      int btg = t >> 6, bl = t & 63;
      unsigned long long* dst =
        (unsigned long long*)&frag[(((btg * 9) + 8) * 64 + bl) * 8];
      dst[0] = (bl < 32) ? 0x3F80ull : 0ull;   // bf16 1.0 at j==0, k<8 half
      dst[1] = 0ull;
    }
  }
  __syncthreads();   // frags + gates ready

  // --- Phase B: MFMA. C[o][token] = sum_h W[h][o] * x[token][h]
  // Both token-groups' x-frags held in regs (72 VGPR) -> e-loop LDS = ZERO.
  // a streamed transiently (1 KB/wave contiguous L2, used twice back-to-back).
  int w = t >> 6, l = t & 63, l32 = l & 31, lh = l >> 5;

  bf16x8 xb0[9], xb1[9];
#pragma unroll
  for (int kt = 0; kt < 9; ++kt){
    xb0[kt] = *(const bf16x8*)&frag[((0 * 9 + kt) * 64 + l) * 8];
    xb1[kt] = *(const bf16x8*)&frag[((1 * 9 + kt) * 64 + l) * 8];
  }
  __syncthreads();   // frag reads done -> tb overlay safe (tb written after e-loop)

  f32x16 zero16;
#pragma unroll
  for (int i = 0; i < 16; ++i) zero16[i] = 0.0f;
  f32x16 tot0 = zero16, tot1 = zero16;

  const bf16x8* pwp = (const bf16x8*)pw;
#pragma unroll 1
  for (int e = 0; e < 8; ++e){
    float g0 = glds[e * 64 + l32];        // 2-way broadcast pair: free
    float g1 = glds[e * 64 + 32 + l32];
    const bf16x8* ap = pwp + ((size_t)(e * 4 + w) * 9) * 64 + l;
    f32x16 p0 = zero16, p1 = zero16;
#pragma unroll
    for (int kt = 0; kt < 9; ++kt){
      bf16x8 a = ap[kt * 64];             // transient: used twice, then dead
      p0 = __builtin_amdgcn_mfma_f32_32x32x16_bf16(a, xb0[kt], p0, 0, 0, 0);
      p1 = __builtin_amdgcn_mfma_f32_32x32x16_bf16(a, xb1[kt], p1, 0, 0, 0);
    }
#pragma unroll
    for (int r = 0; r < 16; ++r){         // static indices only
      tot0[r] += g0 * p0[r];
      tot1[r] += g1 * p1[r];
    }
  }

  // --- epilogue: LDS transpose (XOR swizzle) -> coalesced stores
  // C/D map: token(col)=l32, o(row)=w*32 + rg*8 + lh*4 + rr
  {
#pragma unroll
    for (int rg = 0; rg < 4; ++rg){
      int o = w * 32 + rg * 8 + lh * 4;
      {
        int trow = 0 * 32 + l32;
        int cs = (o >> 2) ^ l32;
        *(float4*)&tb[trow * 128 + cs * 4] =
          make_float4(tot0[rg * 4 + 0], tot0[rg * 4 + 1], tot0[rg * 4 + 2], tot0[rg * 4 + 3]);
      }
      {
        int trow = 1 * 32 + l32;
        int cs = (o >> 2) ^ l32;
        *(float4*)&tb[trow * 128 + cs * 4] =
          make_float4(tot1[rg * 4 + 0], tot1[rg * 4 + 1], tot1[rg * 4 + 2], tot1[rg * 4 + 3]);
      }
    }
  }
  __syncthreads();
#pragma unroll
  for (int i = 0; i < 8; ++i){
    int idx = i * 256 + t;
    int trow = idx >> 5, c = idx & 31;
    int cs = c ^ (trow & 31);
    float4 v = *(float4*)&tb[trow * 128 + cs * 4];
    *(float4*)(out + (tokbase + trow) * ODIM + c * 4) = v;
  }
}

// ---------------------------------------------------------------------------
extern "C" void kernel_launch(void* const* d_in, const int* in_sizes, int n_in,
                              void* d_out, int out_size, void* d_ws, size_t ws_size,
                              hipStream_t stream){
  const float* x  = (const float*)d_in[0];
  const float* wg = (const float*)d_in[1];
  // d_in[2] = w_noise (inactive in eval mode)
  const float* we = (const float*)d_in[3];
  const float* be = (const float*)d_in[4];
  // d_in[5] = top_k (== 2, baked in)
  float* out = (float*)d_out;

  unsigned short* pw = (unsigned short*)d_ws;          // 294,912 B

  pack_w   <<<72,   256, 0, stream>>>(we, be, pw);
  moe_fused<<<2048, 256, 0, stream>>>(x, wg, pw, out);
}